// Round 8
// baseline (1572.728 us; speedup 1.0000x reference)
//
#include <hip/hip_runtime.h>
#include <hip/hip_fp16.h>

#define B_   64
#define NB   128
#define E_   1024
#define DH   300
#define G3   900
#define OUTD 1924
#define SLICES 4
#define PK_STRIDE 1800
#define MROW 160   // u64 words per (b,i): 150 self-tagged data pairs + 8 beta words + 2 pad

typedef _Float16 h2raw __attribute__((ext_vector_type(2)));

__device__ __forceinline__ float dot2f(unsigned int m2, unsigned int w, float acc) {
    h2raw a, b;
    __builtin_memcpy(&a, &m2, 4);
    __builtin_memcpy(&b, &w, 4);
    return __builtin_amdgcn_fdot2(a, b, acc, false);
}

__device__ __forceinline__ unsigned int packh2(float x, float y) {
    __half2 h;
    h.x = __float2half_rn(x);
    h.y = __float2half_rn(y);
    unsigned int u;
    __builtin_memcpy(&u, &h, 4);
    return u;
}

__device__ __forceinline__ float sigmoidf_(float x) { return 1.f / (1.f + __expf(-x)); }
__device__ __forceinline__ float tanh_fast(float x) { return 1.f - 2.f / (__expf(2.f * x) + 1.f); }

// ---------------- copy features into output tail ----------------
__global__ __launch_bounds__(256)
void copy_feat(const float* __restrict__ f, float* __restrict__ out) {
    const long id = (long)blockIdx.x * 256 + threadIdx.x;
    const long r = id >> 8;
    const int  c = (int)(id & 255);
    const float4 v = ((const float4*)(f + r * E_))[c];
    ((float4*)(out + r * OUTD + 3 * DH))[c] = v;
}

// ---------------- pack recurrent weights -> PK2[l][kp(150)][R(1800)] f16-pairs ----------------
__global__ __launch_bounds__(256)
void pack2(const float* __restrict__ gc_whh, const float* __restrict__ gp_wih,
           unsigned int* __restrict__ dst) {
    const int id = blockIdx.x * 256 + threadIdx.x;
    if (id >= 2 * 150 * PK_STRIDE) return;
    const int l   = id / (150 * PK_STRIDE);
    const int rem = id % (150 * PK_STRIDE);
    const int kp  = rem / PK_STRIDE;
    const int R   = rem % PK_STRIDE;
    const int mat = R / G3;
    const int o   = R % G3;
    const float* W = (mat ? gp_wih : gc_whh) + (long)l * G3 * DH;
    const float2 v = *(const float2*)(W + (long)o * DH + 2 * kp);
    dst[id] = packh2(v.x, v.y);
}

// ---------------- GEMM input packing to f16 pairs ----------------
__global__ __launch_bounds__(256)
void pack_af(const float* __restrict__ src, unsigned int* __restrict__ dst) {
    const long id = (long)blockIdx.x * 256 + threadIdx.x;   // 8192*512
    const long r = id >> 9;
    const int kp = (int)(id & 511);
    const float2 v = *(const float2*)(src + r * E_ + 2 * kp);
    dst[id] = packh2(v.x, v.y);
}

__global__ __launch_bounds__(256)
void pack_ah(const float* __restrict__ src, unsigned int* __restrict__ dst) {
    const long id = (long)blockIdx.x * 256 + threadIdx.x;   // 8192*160
    const long r = id / 160;
    const int kp = (int)(id % 160);
    unsigned int u = 0u;
    if (kp < 150) {
        const float2 v = *(const float2*)(src + r * OUTD + 2 * kp);
        u = packh2(v.x, v.y);
    }
    dst[id] = u;
}

__global__ __launch_bounds__(256)
void pack_bf(const float* __restrict__ W, unsigned int* __restrict__ dst) {
    const int id = blockIdx.x * 256 + threadIdx.x;          // 320*512
    const int n = id >> 9;
    const int kp = id & 511;
    unsigned int u = 0u;
    if (n < DH) u = packh2(W[(2 * kp) * DH + n], W[(2 * kp + 1) * DH + n]);
    dst[id] = u;
}

__global__ __launch_bounds__(256)
void pack_bw(const float* __restrict__ W, unsigned int* __restrict__ dst) {
    const int id = blockIdx.x * 256 + threadIdx.x;          // 960*160
    const int n = id / 160;
    const int kp = id % 160;
    unsigned int u = 0u;
    if (n < G3 && kp < 150) {
        const float2 v = *(const float2*)(W + (long)n * DH + 2 * kp);
        u = packh2(v.x, v.y);
    }
    dst[id] = u;
}

// ---------------- f16-dot2 GEMM ----------------
template<int RELU>
__global__ __launch_bounds__(256)
void gemm_h16(const unsigned int* __restrict__ APK, int ldap,
              const unsigned int* __restrict__ BPK, int ldbp,
              const float* __restrict__ bias,
              float* __restrict__ C, int ldc,
              int N, int KP)
{
    __shared__ __align__(16) unsigned int As[16][132];
    __shared__ __align__(16) unsigned int Bs[16][68];
    const int tid = threadIdx.x;
    const int m0 = blockIdx.y * 128;
    const int n0 = blockIdx.x * 64;
    const int tx = tid & 15, ty = tid >> 4;
    const int am = tid >> 1, ak8 = (tid & 1) * 8;
    const int bn = tid >> 2, bk4 = (tid & 3) * 4;

    float acc[8][4] = {{0.f}};
    const unsigned int* ap = APK + (long)(m0 + am) * ldap + ak8;
    const unsigned int* bp = BPK + (long)(n0 + bn) * ldbp + bk4;

    for (int kp0 = 0; kp0 < KP; kp0 += 16) {
        const uint4 a0 = *(const uint4*)(ap + kp0);
        const uint4 a1 = *(const uint4*)(ap + kp0 + 4);
        const uint4 bq = *(const uint4*)(bp + kp0);
        As[ak8 + 0][am] = a0.x; As[ak8 + 1][am] = a0.y;
        As[ak8 + 2][am] = a0.z; As[ak8 + 3][am] = a0.w;
        As[ak8 + 4][am] = a1.x; As[ak8 + 5][am] = a1.y;
        As[ak8 + 6][am] = a1.z; As[ak8 + 7][am] = a1.w;
        Bs[bk4 + 0][bn] = bq.x; Bs[bk4 + 1][bn] = bq.y;
        Bs[bk4 + 2][bn] = bq.z; Bs[bk4 + 3][bn] = bq.w;
        __syncthreads();
        #pragma unroll
        for (int kp = 0; kp < 16; ++kp) {
            const uint4 aA = *(const uint4*)&As[kp][ty * 8];
            const uint4 aB = *(const uint4*)&As[kp][ty * 8 + 4];
            const uint4 bb = *(const uint4*)&Bs[kp][tx * 4];
            const unsigned int av[8] = {aA.x, aA.y, aA.z, aA.w, aB.x, aB.y, aB.z, aB.w};
            const unsigned int bv[4] = {bb.x, bb.y, bb.z, bb.w};
            #pragma unroll
            for (int ii = 0; ii < 8; ++ii)
                #pragma unroll
                for (int jj = 0; jj < 4; ++jj)
                    acc[ii][jj] = dot2f(av[ii], bv[jj], acc[ii][jj]);
        }
        __syncthreads();
    }

    const int gn0 = n0 + tx * 4;
    #pragma unroll
    for (int ii = 0; ii < 8; ++ii) {
        const int gm = m0 + ty * 8 + ii;
        float* cp = C + (long)gm * ldc + gn0;
        if (gn0 + 3 < N) {
            const float4 bb = *(const float4*)&bias[gn0];
            float4 o;
            o.x = acc[ii][0] + bb.x; o.y = acc[ii][1] + bb.y;
            o.z = acc[ii][2] + bb.z; o.w = acc[ii][3] + bb.w;
            if (RELU) { o.x = fmaxf(o.x, 0.f); o.y = fmaxf(o.y, 0.f); o.z = fmaxf(o.z, 0.f); o.w = fmaxf(o.w, 0.f); }
            *(float4*)cp = o;
        } else if (gn0 < N) {
            for (int jj = 0; jj < 4; ++jj) {
                const int gn = gn0 + jj;
                if (gn < N) {
                    float v = acc[ii][jj] + bias[gn];
                    if (RELU) v = fmaxf(v, 0.f);
                    cp[jj] = v;
                }
            }
        }
    }
}

// ---------------- DAG scan v8: self-tagged mailbox words, single L3 round trip, 3 barriers ----------------
// Mailbox per (b,i): u64[MROW]; word w = { payload(32) hi | tag=i+1(32) lo }.
// Words 0..149: f16-pair payloads (pair p covers dims 2p,2p+1; slice k owns pairs [38k, 38k+npairs)).
// Words 150..157: beta partials (slice k, wave w -> word 150+2k+w).
__global__ __launch_bounds__(512, 2)
void scan8(float* __restrict__ out,
           const float* __restrict__ GIC,
           const float* __restrict__ GHP,
           const unsigned int* __restrict__ PK2L,
           const float* __restrict__ cbhh,
           const float* __restrict__ pbih,
           const int* __restrict__ adj,
           const float* __restrict__ wk,
           unsigned long long* __restrict__ TBL,
           int l)
{
    extern __shared__ unsigned int histp[];   // [128][152] f16-pairs
    __shared__ float wsm[NB];
    __shared__ float betas[NB];
    __shared__ float Mlds[DH];
    __shared__ __align__(16) unsigned int M2[152];
    __shared__ float gmv[456];

    const int tid = threadIdx.x;
    const int lane = tid & 63;
    const int wid = tid >> 6;
    const int b = blockIdx.x & 63;
    const int k = blockIdx.x >> 6;
    const int swk = (k == 3) ? 72 : 76;

    float* outb = out + (long)b * NB * OUTD;
    const float* xcol = outb + l * DH;
    float* ycol = outb + (l + 1) * DH;
    const float* gicb = GIC + (long)b * NB * G3;
    const float* ghpb = GHP + (long)b * NB * G3;
    const int* adjb = adj + b * NB * NB;
    unsigned long long* mb = TBL + (long)b * NB * MROW;

    if (tid < 152) M2[tid] = 0u;

    const int D = 76 * k + ((tid < swk) ? tid : 0);
    const float cb0 = cbhh[D], cb1 = cbhh[DH + D], cb2 = cbhh[2 * DH + D];
    const float pb0 = pbih[D], pb1 = pbih[DH + D], pb2 = pbih[2 * DH + D];
    const float wkD = wk[D];

    const int ROWS = 6 * swk;
    int R;
    {
        const int t = (tid < ROWS) ? tid : 0;
        const int d = t % swk;
        const int r = t / swk;
        R = (r / 3) * G3 + (r % 3) * DH + 76 * k + d;
    }
    unsigned int w[152];
    #pragma unroll
    for (int j = 0; j < 150; ++j) w[j] = PK2L[j * PK_STRIDE + R];
    w[150] = 0u; w[151] = 0u;

    __syncthreads();

    for (int i = 0; i < NB; ++i) {
        // ---- prefetch (overlaps poll) ----
        int adj0 = 0, adj1 = 0;
        if (wid == 0 && i > 0) {
            adj0 = adjb[i * NB + lane];
            adj1 = adjb[i * NB + 64 + lane];
        }
        float gi0 = 0, gi1 = 0, gi2 = 0, gp0 = 0, gp1 = 0, gp2 = 0, xi = 0;
        if (tid < swk) {
            const float* gic = gicb + (long)i * G3;
            const float* ghp = ghpb + (long)i * G3;
            gi0 = gic[D]; gi1 = gic[DH + D]; gi2 = gic[2 * DH + D];
            gp0 = ghp[D]; gp1 = ghp[DH + D]; gp2 = ghp[2 * DH + D];
            xi = xcol[(long)i * OUTD + D];
        }

        if (i > 0) {
            if (wid == 0) {
                const unsigned long long* mrow = mb + (long)(i - 1) * MROW;
                const unsigned int tag = (unsigned int)i;
                const int w2i = lane + 128;
                const bool h2 = (w2i < 158);
                unsigned long long v0 = 0, v1 = 0, v2 = 0;
                bool ok0 = false, ok1 = false, ok2 = !h2;
                while (true) {
                    if (!ok0) { v0 = __hip_atomic_load(&mrow[lane],      __ATOMIC_RELAXED, __HIP_MEMORY_SCOPE_AGENT); ok0 = ((unsigned int)v0 == tag); }
                    if (!ok1) { v1 = __hip_atomic_load(&mrow[lane + 64], __ATOMIC_RELAXED, __HIP_MEMORY_SCOPE_AGENT); ok1 = ((unsigned int)v1 == tag); }
                    if (!ok2) { v2 = __hip_atomic_load(&mrow[w2i],       __ATOMIC_RELAXED, __HIP_MEMORY_SCOPE_AGENT); ok2 = ((unsigned int)v2 == tag); }
                    if (__all(ok0 && ok1 && ok2)) break;
                }
                // beta = sum of 8 partial words (word 150..157 <-> lanes 22..29 third word)
                float bw = 0.f;
                if (lane >= 22 && lane < 30) {
                    const unsigned int hb = (unsigned int)(v2 >> 32);
                    __builtin_memcpy(&bw, &hb, 4);
                }
                #pragma unroll
                for (int off = 32; off; off >>= 1) bw += __shfl_xor(bw, off);
                const float beta_new = bw;
                if (lane == 0) betas[i - 1] = beta_new;

                // history row i-1 -> LDS
                histp[(i - 1) * 152 + lane]      = (unsigned int)(v0 >> 32);
                histp[(i - 1) * 152 + lane + 64] = (unsigned int)(v1 >> 32);
                if (lane < 22)
                    histp[(i - 1) * 152 + lane + 128] = (unsigned int)(v2 >> 32);

                // wave0 softmax over j < i (base term cancels)
                const int j1 = lane + 64;
                const bool vv0 = (lane < i) && (adj0 != 0);
                const bool vv1 = (j1 < i) && (adj1 != 0);
                const float bb0 = (lane == i - 1) ? beta_new : betas[lane];
                const float bb1 = (j1 == i - 1) ? beta_new : betas[j1 & (NB - 1)];
                float a0 = vv0 ? bb0 : -3.0e38f;
                float a1 = vv1 ? bb1 : -3.0e38f;
                float mx = fmaxf(a0, a1);
                #pragma unroll
                for (int off = 32; off; off >>= 1) mx = fmaxf(mx, __shfl_xor(mx, off));
                const float e0 = vv0 ? __expf(a0 - mx) : 0.f;
                const float e1 = vv1 ? __expf(a1 - mx) : 0.f;
                float s = e0 + e1;
                #pragma unroll
                for (int off = 32; off; off >>= 1) s += __shfl_xor(s, off);
                const float inv = 1.f / s;
                wsm[lane] = e0 * inv;
                wsm[j1]   = e1 * inv;
            }
            __syncthreads();   // B1: wsm + history row i-1 ready

            if (tid < 150) {
                float m0 = 0.f, m1 = 0.f;
                #pragma unroll 4
                for (int j = 0; j < i; ++j) {
                    const unsigned int u = histp[j * 152 + tid];
                    __half2 h;
                    __builtin_memcpy(&h, &u, 4);
                    const float wj = wsm[j];
                    m0 = fmaf(wj, __half2float(h.x), m0);
                    m1 = fmaf(wj, __half2float(h.y), m1);
                }
                Mlds[2 * tid] = m0;
                Mlds[2 * tid + 1] = m1;
                M2[tid] = packh2(m0, m1);
            }
        } else {
            if (tid < DH) Mlds[tid] = 0.f;
        }
        __syncthreads();   // B4: M ready

        if (tid < ROWS) {
            float a0 = 0.f, a1 = 0.f;
            #pragma unroll
            for (int j4 = 0; j4 < 152; j4 += 4) {
                const uint4 m4 = *(const uint4*)&M2[j4];
                a0 = dot2f(m4.x, w[j4 + 0], a0);
                a1 = dot2f(m4.y, w[j4 + 1], a1);
                a0 = dot2f(m4.z, w[j4 + 2], a0);
                a1 = dot2f(m4.w, w[j4 + 3], a1);
            }
            gmv[tid] = a0 + a1;
        }
        __syncthreads();   // B5: gmv ready

        float rowv = 0.f;
        if (tid < swk) {
            const float Mi = Mlds[D];
            const float hc0 = gmv[0 * swk + tid] + cb0;
            const float hc1 = gmv[1 * swk + tid] + cb1;
            const float hc2 = gmv[2 * swk + tid] + cb2;
            const float rc = sigmoidf_(gi0 + hc0);
            const float zc = sigmoidf_(gi1 + hc1);
            const float nc = tanh_fast(gi2 + rc * hc2);
            const float Cc = (1.f - zc) * nc + zc * Mi;
            const float ip0 = gmv[3 * swk + tid] + pb0;
            const float ip1 = gmv[4 * swk + tid] + pb1;
            const float ip2 = gmv[5 * swk + tid] + pb2;
            const float rp = sigmoidf_(ip0 + gp0);
            const float zp = sigmoidf_(ip1 + gp1);
            const float np = tanh_fast(ip2 + rp * gp2);
            const float Pp = (1.f - zp) * np + zp * xi;
            rowv = Cc + Pp;
            ycol[(long)i * OUTD + D] = rowv;   // off critical path
        }
        // ---- ship self-tagged data words (no drain, no tag store, no barrier) ----
        {
            const unsigned long long tagw = (unsigned long long)(unsigned int)(i + 1);
            const float pr = __shfl_xor(rowv, 1);
            const unsigned int pairu32 = packh2(rowv, pr);
            if (tid < swk && !(tid & 1)) {
                const unsigned long long d = ((unsigned long long)pairu32 << 32) | tagw;
                __hip_atomic_store(&mb[(long)i * MROW + 38 * k + (tid >> 1)], d,
                                   __ATOMIC_RELAXED, __HIP_MEMORY_SCOPE_AGENT);
            }
            // per-wave beta partial
            float bv = (tid < swk) ? rowv * wkD : 0.f;
            if (wid < 2) {
                #pragma unroll
                for (int off = 32; off; off >>= 1) bv += __shfl_xor(bv, off);
                if (lane == 0) {
                    unsigned int bbits;
                    __builtin_memcpy(&bbits, &bv, 4);
                    const unsigned long long d = ((unsigned long long)bbits << 32) | tagw;
                    __hip_atomic_store(&mb[(long)i * MROW + 150 + 2 * k + wid], d,
                                       __ATOMIC_RELAXED, __HIP_MEMORY_SCOPE_AGENT);
                }
            }
        }
        // no end-of-step barrier: next iteration's B1/B4/B5 order all LDS reuse
    }
}

extern "C" void kernel_launch(void* const* d_in, const int* in_sizes, int n_in,
                              void* d_out, int out_size, void* d_ws, size_t ws_size,
                              hipStream_t stream) {
    (void)in_sizes; (void)n_in; (void)out_size; (void)ws_size;
    const float* features = (const float*)d_in[0];
    const float* fc1_w    = (const float*)d_in[1];
    const float* fc1_b    = (const float*)d_in[2];
    const float* gat_w    = (const float*)d_in[3];
    const float* gc_wih   = (const float*)d_in[5];
    const float* gc_whh   = (const float*)d_in[6];
    const float* gc_bih   = (const float*)d_in[7];
    const float* gc_bhh   = (const float*)d_in[8];
    const float* gp_wih   = (const float*)d_in[9];
    const float* gp_whh   = (const float*)d_in[10];
    const float* gp_bih   = (const float*)d_in[11];
    const float* gp_bhh   = (const float*)d_in[12];
    const int*   adj      = (const int*)d_in[13];
    float* out = (float*)d_out;

    unsigned long long* TB = (unsigned long long*)d_ws;            // 2*64*128*160 u64
    float* GIC = (float*)(TB + 2L * B_ * NB * MROW);               // 64*128*900 f32
    float* GHP = GIC + (long)B_ * NB * G3;
    unsigned int* PK2  = (unsigned int*)(GHP + (long)B_ * NB * G3); // 2*150*1800
    unsigned int* APK2 = PK2 + 2 * 150 * PK_STRIDE;                 // 8192*160
    unsigned int* BPKF = APK2 + 8192L * 160;                        // 320*512
    unsigned int* BPKL = BPKF + 320L * 512;                         // 4*960*160
    unsigned int* APK1 = (unsigned int*)GIC;                        // alias: 8192*512 <= GIC size

    hipFuncSetAttribute(reinterpret_cast<const void*>(scan8),
                        hipFuncAttributeMaxDynamicSharedMemorySize, 80000);
    hipMemsetAsync(TB, 0, 2L * B_ * NB * MROW * sizeof(unsigned long long), stream);

    copy_feat<<<dim3((B_ * NB * E_) / 1024), 256, 0, stream>>>(features, out);
    pack2<<<dim3((2 * 150 * PK_STRIDE + 255) / 256), 256, 0, stream>>>(gc_whh, gp_wih, PK2);

    // pack GEMM inputs
    pack_af<<<dim3(8192 * 512 / 256), 256, 0, stream>>>(features, APK1);
    pack_bf<<<dim3(320 * 512 / 256), 256, 0, stream>>>(fc1_w, BPKF);
    pack_bw<<<dim3(960 * 160 / 256), 256, 0, stream>>>(gc_wih,               BPKL + 0L * 153600);
    pack_bw<<<dim3(960 * 160 / 256), 256, 0, stream>>>(gp_whh,               BPKL + 1L * 153600);
    pack_bw<<<dim3(960 * 160 / 256), 256, 0, stream>>>(gc_wih + G3 * DH,     BPKL + 2L * 153600);
    pack_bw<<<dim3(960 * 160 / 256), 256, 0, stream>>>(gp_whh + G3 * DH,     BPKL + 3L * 153600);

    // H0 = relu(features @ fc1_w + b) -> out cols [0,300)
    gemm_h16<1><<<dim3(5, 64), 256, 0, stream>>>(APK1, 512, BPKF, 512, fc1_b, out, OUTD, DH, 512);

    for (int l = 0; l < 2; ++l) {
        pack_ah<<<dim3(8192 * 160 / 256), 256, 0, stream>>>(out + l * DH, APK2);
        gemm_h16<0><<<dim3(15, 64), 256, 0, stream>>>(
            APK2, 160, BPKL + (2L * l) * 153600, 160, gc_bih + l * G3, GIC, G3, G3, 160);
        gemm_h16<0><<<dim3(15, 64), 256, 0, stream>>>(
            APK2, 160, BPKL + (2L * l + 1) * 153600, 160, gp_bhh + l * G3, GHP, G3, G3, 160);
        scan8<<<dim3(SLICES * B_), 512, 77824, stream>>>(
            out, GIC, GHP, PK2 + (long)l * 150 * PK_STRIDE,
            gc_bhh + l * G3, gp_bih + l * G3, adj,
            gat_w + l * 2 * DH + DH,
            TB + (long)l * B_ * NB * MROW, l);
    }
}

// Round 9
// 1218.173 us; speedup vs baseline: 1.2911x; 1.2911x over previous
//
#include <hip/hip_runtime.h>
#include <hip/hip_fp16.h>

#define B_   64
#define NB   128
#define E_   1024
#define DH   300
#define G3   900
#define OUTD 1924
#define SLICES 4
#define PK_STRIDE 1800
#define MROW 160   // u64/row: u32 data words [0..149], tags u64 words [152..159] (one 64B line)

typedef _Float16 h2raw __attribute__((ext_vector_type(2)));

__device__ __forceinline__ float dot2f(unsigned int m2, unsigned int w, float acc) {
    h2raw a, b;
    __builtin_memcpy(&a, &m2, 4);
    __builtin_memcpy(&b, &w, 4);
    return __builtin_amdgcn_fdot2(a, b, acc, false);
}

__device__ __forceinline__ unsigned int packh2(float x, float y) {
    __half2 h;
    h.x = __float2half_rn(x);
    h.y = __float2half_rn(y);
    unsigned int u;
    __builtin_memcpy(&u, &h, 4);
    return u;
}

__device__ __forceinline__ float sigmoidf_(float x) { return 1.f / (1.f + __expf(-x)); }
__device__ __forceinline__ float tanh_fast(float x) { return 1.f - 2.f / (__expf(2.f * x) + 1.f); }

// ---------------- copy features into output tail ----------------
__global__ __launch_bounds__(256)
void copy_feat(const float* __restrict__ f, float* __restrict__ out) {
    const long id = (long)blockIdx.x * 256 + threadIdx.x;
    const long r = id >> 8;
    const int  c = (int)(id & 255);
    const float4 v = ((const float4*)(f + r * E_))[c];
    ((float4*)(out + r * OUTD + 3 * DH))[c] = v;
}

// ---------------- pack recurrent weights -> PK2[l][kp(150)][R(1800)] f16-pairs ----------------
__global__ __launch_bounds__(256)
void pack2(const float* __restrict__ gc_whh, const float* __restrict__ gp_wih,
           unsigned int* __restrict__ dst) {
    const int id = blockIdx.x * 256 + threadIdx.x;
    if (id >= 2 * 150 * PK_STRIDE) return;
    const int l   = id / (150 * PK_STRIDE);
    const int rem = id % (150 * PK_STRIDE);
    const int kp  = rem / PK_STRIDE;
    const int R   = rem % PK_STRIDE;
    const int mat = R / G3;
    const int o   = R % G3;
    const float* W = (mat ? gp_wih : gc_whh) + (long)l * G3 * DH;
    const float2 v = *(const float2*)(W + (long)o * DH + 2 * kp);
    dst[id] = packh2(v.x, v.y);
}

// ---------------- GEMM input packing to f16 pairs ----------------
__global__ __launch_bounds__(256)
void pack_af(const float* __restrict__ src, unsigned int* __restrict__ dst) {
    const long id = (long)blockIdx.x * 256 + threadIdx.x;   // 8192*512
    const long r = id >> 9;
    const int kp = (int)(id & 511);
    const float2 v = *(const float2*)(src + r * E_ + 2 * kp);
    dst[id] = packh2(v.x, v.y);
}

__global__ __launch_bounds__(256)
void pack_ah(const float* __restrict__ src, unsigned int* __restrict__ dst) {
    const long id = (long)blockIdx.x * 256 + threadIdx.x;   // 8192*160
    const long r = id / 160;
    const int kp = (int)(id % 160);
    unsigned int u = 0u;
    if (kp < 150) {
        const float2 v = *(const float2*)(src + r * OUTD + 2 * kp);
        u = packh2(v.x, v.y);
    }
    dst[id] = u;
}

__global__ __launch_bounds__(256)
void pack_bf(const float* __restrict__ W, unsigned int* __restrict__ dst) {
    const int id = blockIdx.x * 256 + threadIdx.x;          // 320*512
    const int n = id >> 9;
    const int kp = id & 511;
    unsigned int u = 0u;
    if (n < DH) u = packh2(W[(2 * kp) * DH + n], W[(2 * kp + 1) * DH + n]);
    dst[id] = u;
}

__global__ __launch_bounds__(256)
void pack_bw(const float* __restrict__ W, unsigned int* __restrict__ dst) {
    const int id = blockIdx.x * 256 + threadIdx.x;          // 960*160
    const int n = id / 160;
    const int kp = id % 160;
    unsigned int u = 0u;
    if (n < G3 && kp < 150) {
        const float2 v = *(const float2*)(W + (long)n * DH + 2 * kp);
        u = packh2(v.x, v.y);
    }
    dst[id] = u;
}

// ---------------- f16-dot2 GEMM ----------------
template<int RELU>
__global__ __launch_bounds__(256)
void gemm_h16(const unsigned int* __restrict__ APK, int ldap,
              const unsigned int* __restrict__ BPK, int ldbp,
              const float* __restrict__ bias,
              float* __restrict__ C, int ldc,
              int N, int KP)
{
    __shared__ __align__(16) unsigned int As[16][132];
    __shared__ __align__(16) unsigned int Bs[16][68];
    const int tid = threadIdx.x;
    const int m0 = blockIdx.y * 128;
    const int n0 = blockIdx.x * 64;
    const int tx = tid & 15, ty = tid >> 4;
    const int am = tid >> 1, ak8 = (tid & 1) * 8;
    const int bn = tid >> 2, bk4 = (tid & 3) * 4;

    float acc[8][4] = {{0.f}};
    const unsigned int* ap = APK + (long)(m0 + am) * ldap + ak8;
    const unsigned int* bp = BPK + (long)(n0 + bn) * ldbp + bk4;

    for (int kp0 = 0; kp0 < KP; kp0 += 16) {
        const uint4 a0 = *(const uint4*)(ap + kp0);
        const uint4 a1 = *(const uint4*)(ap + kp0 + 4);
        const uint4 bq = *(const uint4*)(bp + kp0);
        As[ak8 + 0][am] = a0.x; As[ak8 + 1][am] = a0.y;
        As[ak8 + 2][am] = a0.z; As[ak8 + 3][am] = a0.w;
        As[ak8 + 4][am] = a1.x; As[ak8 + 5][am] = a1.y;
        As[ak8 + 6][am] = a1.z; As[ak8 + 7][am] = a1.w;
        Bs[bk4 + 0][bn] = bq.x; Bs[bk4 + 1][bn] = bq.y;
        Bs[bk4 + 2][bn] = bq.z; Bs[bk4 + 3][bn] = bq.w;
        __syncthreads();
        #pragma unroll
        for (int kp = 0; kp < 16; ++kp) {
            const uint4 aA = *(const uint4*)&As[kp][ty * 8];
            const uint4 aB = *(const uint4*)&As[kp][ty * 8 + 4];
            const uint4 bb = *(const uint4*)&Bs[kp][tx * 4];
            const unsigned int av[8] = {aA.x, aA.y, aA.z, aA.w, aB.x, aB.y, aB.z, aB.w};
            const unsigned int bv[4] = {bb.x, bb.y, bb.z, bb.w};
            #pragma unroll
            for (int ii = 0; ii < 8; ++ii)
                #pragma unroll
                for (int jj = 0; jj < 4; ++jj)
                    acc[ii][jj] = dot2f(av[ii], bv[jj], acc[ii][jj]);
        }
        __syncthreads();
    }

    const int gn0 = n0 + tx * 4;
    #pragma unroll
    for (int ii = 0; ii < 8; ++ii) {
        const int gm = m0 + ty * 8 + ii;
        float* cp = C + (long)gm * ldc + gn0;
        if (gn0 + 3 < N) {
            const float4 bb = *(const float4*)&bias[gn0];
            float4 o;
            o.x = acc[ii][0] + bb.x; o.y = acc[ii][1] + bb.y;
            o.z = acc[ii][2] + bb.z; o.w = acc[ii][3] + bb.w;
            if (RELU) { o.x = fmaxf(o.x, 0.f); o.y = fmaxf(o.y, 0.f); o.z = fmaxf(o.z, 0.f); o.w = fmaxf(o.w, 0.f); }
            *(float4*)cp = o;
        } else if (gn0 < N) {
            for (int jj = 0; jj < 4; ++jj) {
                const int gn = gn0 + jj;
                if (gn < N) {
                    float v = acc[ii][jj] + bias[gn];
                    if (RELU) v = fmaxf(v, 0.f);
                    cp[jj] = v;
                }
            }
        }
    }
}

// ---------------- DAG scan v9: per-wave early release + precomputed softmax + poll-overlapped M-sum ----------------
// Exchange (v7 format): u32 data words [0..149] at row base; 8 tag u64s at words 152..159
// ({beta_partial(hi)|tag=i+1(lo)}, word 152+2k+w for slice k wave w), tags stored after per-wave vmcnt drain.
// Roles/step: wave0 poll+ingest | waves4-6 V-loop (j<=i-2, weights wsm2 from prev step) | B1 |
// V-finalize (late j=i-1, online rescale) | B4 | matvec | B5 | gates+release (w0,w1) || prep wsm2 (w2) | B6.
__global__ __launch_bounds__(512, 2)
void scan9(float* __restrict__ out,
           const float* __restrict__ GIC,
           const float* __restrict__ GHP,
           const unsigned int* __restrict__ PK2L,
           const float* __restrict__ cbhh,
           const float* __restrict__ pbih,
           const int* __restrict__ adj,
           const float* __restrict__ wk,
           unsigned long long* __restrict__ TBL,
           int l)
{
    extern __shared__ unsigned int histp[];   // [128][152] f16-pairs
    __shared__ float wsm2[NB];                // unnormalized exp(beta_j - mx2) for next step
    __shared__ float betas[NB];
    __shared__ float Mlds[DH];
    __shared__ __align__(16) unsigned int M2[152];
    __shared__ float gmv[456];
    __shared__ float mx2s, S_pres;

    const int tid = threadIdx.x;
    const int lane = tid & 63;
    const int wid = tid >> 6;
    const int b = blockIdx.x & 63;
    const int k = blockIdx.x >> 6;
    const int swk = (k == 3) ? 72 : 76;

    float* outb = out + (long)b * NB * OUTD;
    const float* xcol = outb + l * DH;
    float* ycol = outb + (l + 1) * DH;
    const float* gicb = GIC + (long)b * NB * G3;
    const float* ghpb = GHP + (long)b * NB * G3;
    const int* adjb = adj + b * NB * NB;
    unsigned long long* mb = TBL + (long)b * NB * MROW;
    unsigned int* mb32 = (unsigned int*)mb;

    if (tid < 152) M2[tid] = 0u;

    const int D = 76 * k + ((tid < swk) ? tid : 0);
    const float cb0 = cbhh[D], cb1 = cbhh[DH + D], cb2 = cbhh[2 * DH + D];
    const float pb0 = pbih[D], pb1 = pbih[DH + D], pb2 = pbih[2 * DH + D];
    const float wkD = wk[D];

    const int ROWS = 6 * swk;
    int R;
    {
        const int t = (tid < ROWS) ? tid : 0;
        const int d = t % swk;
        const int r = t / swk;
        R = (r / 3) * G3 + (r % 3) * DH + 76 * k + d;
    }
    unsigned int w[152];
    #pragma unroll
    for (int j = 0; j < 150; ++j) w[j] = PK2L[j * PK_STRIDE + R];
    w[150] = 0u; w[151] = 0u;

    __syncthreads();

    const bool isv = (tid >= 256) && (tid < 406);
    const int vt = tid - 256;

    for (int i = 0; i < NB; ++i) {
        // ---- top-of-step prefetches ----
        float gi0 = 0, gi1 = 0, gi2 = 0, gp0 = 0, gp1 = 0, gp2 = 0, xi = 0;
        if (tid < swk) {
            const float* gic = gicb + (long)i * G3;
            const float* ghp = ghpb + (long)i * G3;
            gi0 = gic[D]; gi1 = gic[DH + D]; gi2 = gic[2 * DH + D];
            gp0 = ghp[D]; gp1 = ghp[DH + D]; gp2 = ghp[2 * DH + D];
            xi = xcol[(long)i * OUTD + D];
        }
        int a0p = 0, a1p = 0;
        if (wid == 2 && i + 1 < NB) {          // adj row i+1 for prep
            a0p = adjb[(i + 1) * NB + lane];
            a1p = adjb[(i + 1) * NB + 64 + lane];
        }

        if (i > 0) {
            float V0 = 0.f, V1 = 0.f;
            if (wid == 0) {
                // ---- poll 8 self-describing tag words (one 64B line) ----
                const unsigned long long* trow = mb + (long)(i - 1) * MROW;
                const unsigned int tag = (unsigned int)i;
                const bool act = (lane < 8);
                unsigned long long tv = 0;
                while (true) {
                    if (act && (unsigned int)tv != tag)
                        tv = __hip_atomic_load(&trow[152 + lane],
                                               __ATOMIC_RELAXED, __HIP_MEMORY_SCOPE_AGENT);
                    if (__all(!act || (unsigned int)tv == tag)) break;
                }
                float bp = 0.f;
                if (act) {
                    const unsigned int hb = (unsigned int)(tv >> 32);
                    __builtin_memcpy(&bp, &hb, 4);
                }
                bp += __shfl_xor(bp, 1);
                bp += __shfl_xor(bp, 2);
                bp += __shfl_xor(bp, 4);
                if (lane == 0) betas[i - 1] = __shfl(bp, 0);

                // ---- load data words, write history row i-1 ----
                unsigned long long d0 = 0, d1 = 0;
                if (lane < 38) {
                    d0 = __hip_atomic_load(&trow[2 * lane],
                                           __ATOMIC_RELAXED, __HIP_MEMORY_SCOPE_AGENT);
                    d1 = __hip_atomic_load(&trow[2 * lane + 1],
                                           __ATOMIC_RELAXED, __HIP_MEMORY_SCOPE_AGENT);
                    uint4 q;
                    q.x = (unsigned int)d0; q.y = (unsigned int)(d0 >> 32);
                    q.z = (unsigned int)d1; q.w = (unsigned int)(d1 >> 32);
                    *(uint4*)&histp[(i - 1) * 152 + 4 * lane] = q;
                }
            } else if (isv) {
                // ---- V-loop over j <= i-2 with precomputed unnormalized weights ----
                #pragma unroll 4
                for (int j = 0; j + 1 < i; ++j) {
                    const float wj = wsm2[j];
                    const unsigned int u = histp[j * 152 + vt];
                    __half2 h; __builtin_memcpy(&h, &u, 4);
                    V0 = fmaf(wj, __half2float(h.x), V0);
                    V1 = fmaf(wj, __half2float(h.y), V1);
                }
            }
            __syncthreads();   // B1: betas[i-1] + hist row i-1 visible

            if (isv) {
                // ---- finalize: late term j = i-1 (always valid), normalize ----
                const float beta_new = betas[i - 1];
                const float mxl = mx2s;
                float S = S_pres, e;
                if (beta_new > mxl) {
                    const float sc = __expf(mxl - beta_new);   // 0 if mxl = -3e38
                    V0 *= sc; V1 *= sc; S *= sc; e = 1.f;
                } else {
                    e = __expf(beta_new - mxl);
                }
                const unsigned int u = histp[(i - 1) * 152 + vt];
                __half2 h; __builtin_memcpy(&h, &u, 4);
                S += e;
                V0 = fmaf(e, __half2float(h.x), V0);
                V1 = fmaf(e, __half2float(h.y), V1);
                const float inv = 1.f / S;
                const float m0 = V0 * inv, m1 = V1 * inv;
                Mlds[2 * vt] = m0;
                Mlds[2 * vt + 1] = m1;
                M2[vt] = packh2(m0, m1);
            }
        } else {
            if (tid < DH) Mlds[tid] = 0.f;     // M2 pre-zeroed at init
        }
        __syncthreads();   // B4: M ready

        // ---- matvec from register weights ----
        if (tid < ROWS) {
            float a0 = 0.f, a1 = 0.f;
            #pragma unroll
            for (int j4 = 0; j4 < 152; j4 += 4) {
                const uint4 m4 = *(const uint4*)&M2[j4];
                a0 = dot2f(m4.x, w[j4 + 0], a0);
                a1 = dot2f(m4.y, w[j4 + 1], a1);
                a0 = dot2f(m4.z, w[j4 + 2], a0);
                a1 = dot2f(m4.w, w[j4 + 3], a1);
            }
            gmv[tid] = a0 + a1;
        }
        __syncthreads();   // B5: gmv ready

        // ---- gates + per-wave early release (waves 0-1) || prep next step's softmax (wave 2) ----
        if (wid < 2) {
            float rowv = 0.f;
            if (tid < swk) {
                const float Mi = Mlds[D];
                const float hc0 = gmv[0 * swk + tid] + cb0;
                const float hc1 = gmv[1 * swk + tid] + cb1;
                const float hc2 = gmv[2 * swk + tid] + cb2;
                const float rc = sigmoidf_(gi0 + hc0);
                const float zc = sigmoidf_(gi1 + hc1);
                const float nc = tanh_fast(gi2 + rc * hc2);
                const float Cc = (1.f - zc) * nc + zc * Mi;
                const float ip0 = gmv[3 * swk + tid] + pb0;
                const float ip1 = gmv[4 * swk + tid] + pb1;
                const float ip2 = gmv[5 * swk + tid] + pb2;
                const float rp = sigmoidf_(ip0 + gp0);
                const float zp = sigmoidf_(ip1 + gp1);
                const float np = tanh_fast(ip2 + rp * gp2);
                const float Pp = (1.f - zp) * np + zp * xi;
                rowv = Cc + Pp;
            }
            // data stores (v7 format: u32 pair words at row base)
            const float pr = __shfl_xor(rowv, 1);
            const unsigned int pairu32 = packh2(rowv, pr);
            if (tid < swk && !(tid & 1)) {
                __hip_atomic_store(&mb32[(long)i * (MROW * 2) + 38 * k + (tid >> 1)], pairu32,
                                   __ATOMIC_RELAXED, __HIP_MEMORY_SCOPE_AGENT);
            }
            // per-wave beta partial (computed while stores are in flight)
            float bv = (tid < swk) ? rowv * wkD : 0.f;
            #pragma unroll
            for (int off = 32; off; off >>= 1) bv += __shfl_xor(bv, off);
            // wave-local drain, then self-describing tag
            asm volatile("s_waitcnt vmcnt(0)" ::: "memory");
            if (lane == 0) {
                unsigned int bbits;
                __builtin_memcpy(&bbits, &bv, 4);
                const unsigned long long pkt =
                    ((unsigned long long)bbits << 32) | (unsigned int)(i + 1);
                __hip_atomic_store(&mb[(long)i * MROW + 152 + 2 * k + wid], pkt,
                                   __ATOMIC_RELAXED, __HIP_MEMORY_SCOPE_AGENT);
            }
            if (tid < swk) ycol[(long)i * OUTD + D] = rowv;   // fire-and-forget
        } else if (wid == 2 && i + 1 < NB) {
            // prep for step i+1: unnormalized masked softmax over j <= i-1
            const int j1 = lane + 64;
            const bool v0 = (lane < i) && (a0p != 0);
            const bool v1 = (j1 < i) && (a1p != 0);
            const float aa0 = v0 ? betas[lane] : -3.0e38f;
            const float aa1 = v1 ? betas[j1]   : -3.0e38f;
            float mx = fmaxf(aa0, aa1);
            #pragma unroll
            for (int off = 32; off; off >>= 1) mx = fmaxf(mx, __shfl_xor(mx, off));
            const float e0 = v0 ? __expf(aa0 - mx) : 0.f;
            const float e1 = v1 ? __expf(aa1 - mx) : 0.f;
            float s = e0 + e1;
            #pragma unroll
            for (int off = 32; off; off >>= 1) s += __shfl_xor(s, off);
            wsm2[lane] = e0;
            wsm2[j1]   = e1;
            if (lane == 0) { mx2s = mx; S_pres = s; }
        }
        __syncthreads();   // B6: wsm2/mx2s/S_pres ordered for next step's V-loop
    }
}

extern "C" void kernel_launch(void* const* d_in, const int* in_sizes, int n_in,
                              void* d_out, int out_size, void* d_ws, size_t ws_size,
                              hipStream_t stream) {
    (void)in_sizes; (void)n_in; (void)out_size; (void)ws_size;
    const float* features = (const float*)d_in[0];
    const float* fc1_w    = (const float*)d_in[1];
    const float* fc1_b    = (const float*)d_in[2];
    const float* gat_w    = (const float*)d_in[3];
    const float* gc_wih   = (const float*)d_in[5];
    const float* gc_whh   = (const float*)d_in[6];
    const float* gc_bih   = (const float*)d_in[7];
    const float* gc_bhh   = (const float*)d_in[8];
    const float* gp_wih   = (const float*)d_in[9];
    const float* gp_whh   = (const float*)d_in[10];
    const float* gp_bih   = (const float*)d_in[11];
    const float* gp_bhh   = (const float*)d_in[12];
    const int*   adj      = (const int*)d_in[13];
    float* out = (float*)d_out;

    unsigned long long* TB = (unsigned long long*)d_ws;            // 2*64*128*160 u64
    float* GIC = (float*)(TB + 2L * B_ * NB * MROW);               // 64*128*900 f32
    float* GHP = GIC + (long)B_ * NB * G3;
    unsigned int* PK2  = (unsigned int*)(GHP + (long)B_ * NB * G3); // 2*150*1800
    unsigned int* APK2 = PK2 + 2 * 150 * PK_STRIDE;                 // 8192*160
    unsigned int* BPKF = APK2 + 8192L * 160;                        // 320*512
    unsigned int* BPKL = BPKF + 320L * 512;                         // 4*960*160
    unsigned int* APK1 = (unsigned int*)GIC;                        // alias: 8192*512 <= GIC size

    hipFuncSetAttribute(reinterpret_cast<const void*>(scan9),
                        hipFuncAttributeMaxDynamicSharedMemorySize, 80000);
    hipMemsetAsync(TB, 0, 2L * B_ * NB * MROW * sizeof(unsigned long long), stream);

    copy_feat<<<dim3((B_ * NB * E_) / 1024), 256, 0, stream>>>(features, out);
    pack2<<<dim3((2 * 150 * PK_STRIDE + 255) / 256), 256, 0, stream>>>(gc_whh, gp_wih, PK2);

    // pack GEMM inputs
    pack_af<<<dim3(8192 * 512 / 256), 256, 0, stream>>>(features, APK1);
    pack_bf<<<dim3(320 * 512 / 256), 256, 0, stream>>>(fc1_w, BPKF);
    pack_bw<<<dim3(960 * 160 / 256), 256, 0, stream>>>(gc_wih,               BPKL + 0L * 153600);
    pack_bw<<<dim3(960 * 160 / 256), 256, 0, stream>>>(gp_whh,               BPKL + 1L * 153600);
    pack_bw<<<dim3(960 * 160 / 256), 256, 0, stream>>>(gc_wih + G3 * DH,     BPKL + 2L * 153600);
    pack_bw<<<dim3(960 * 160 / 256), 256, 0, stream>>>(gp_whh + G3 * DH,     BPKL + 3L * 153600);

    // H0 = relu(features @ fc1_w + b) -> out cols [0,300)
    gemm_h16<1><<<dim3(5, 64), 256, 0, stream>>>(APK1, 512, BPKF, 512, fc1_b, out, OUTD, DH, 512);

    for (int l = 0; l < 2; ++l) {
        pack_ah<<<dim3(8192 * 160 / 256), 256, 0, stream>>>(out + l * DH, APK2);
        gemm_h16<0><<<dim3(15, 64), 256, 0, stream>>>(
            APK2, 160, BPKL + (2L * l) * 153600, 160, gc_bih + l * G3, GIC, G3, G3, 160);
        gemm_h16<0><<<dim3(15, 64), 256, 0, stream>>>(
            APK2, 160, BPKL + (2L * l + 1) * 153600, 160, gp_bhh + l * G3, GHP, G3, G3, 160);
        scan9<<<dim3(SLICES * B_), 512, 77824, stream>>>(
            out, GIC, GHP, PK2 + (long)l * 150 * PK_STRIDE,
            gc_bhh + l * G3, gp_bih + l * G3, adj,
            gat_w + l * 2 * DH + DH,
            TB + (long)l * B_ * NB * MROW, l);
    }
}